// Round 3
// baseline (508.678 us; speedup 1.0000x reference)
//
#include <hip/hip_runtime.h>
#include <hip/hip_bf16.h>
#include <math.h>

#define N_NODES 4096
#define F_INN   256
#define F_OUTT  64
#define HID     64
#define MAXDEG  64

// Scratch in device globals (no ws_size dependence). Fully rewritten each call.
__device__ int    g_mode;                    // 0 = fp32 inputs, 1 = bf16 inputs
__device__ float  g_Wh [N_NODES * F_OUTT];
__device__ float  g_Wh2[N_NODES * F_OUTT];
__device__ float  g_s1 [N_NODES];
__device__ float  g_s2 [N_NODES];
__device__ int    g_rev[N_NODES * MAXDEG];
__device__ int    g_perm[N_NODES];
__device__ float4 g_GX [N_NODES * F_OUTT];   // per (node, unit): quad {i,f,g,o}

__device__ __forceinline__ float bf2f(unsigned short u) {
  union { unsigned int i; float f; } v; v.i = ((unsigned int)u) << 16; return v.f;
}

template<bool BF16>
__device__ __forceinline__ float ldf(const void* p, int i) {
  if constexpr (BF16) return bf2f(((const unsigned short*)p)[i]);
  else                return ((const float*)p)[i];
}

__device__ __forceinline__ float bcastf(float v, int l) {
#if __has_builtin(__builtin_amdgcn_readlane)
  return __int_as_float(__builtin_amdgcn_readlane(__float_as_int(v), l));
#else
  return __shfl(v, l);
#endif
}

__device__ __forceinline__ float sigm(float x) { return 1.f / (1.f + __expf(-x)); }
__device__ __forceinline__ float tanh_fast(float x) { return 1.f - 2.f / (1.f + __expf(2.f * x)); }

// D0: dtype detector. fp32 adj words are exactly 0x00000000 / 0x3F800000
// (low 16 bits always zero). bf16 adj has ~500 nonzero low-halves in the
// first 65536 words (elements at even index equal to 1.0 -> 0x3F80).
__global__ __launch_bounds__(256) void k_detect(const unsigned int* __restrict__ aw) {
  __shared__ int any;
  if (threadIdx.x == 0) any = 0;
  __syncthreads();
  int loc = 0;
  for (int i = threadIdx.x; i < 65536; i += 256)
    loc |= ((aw[i] & 0xFFFFu) != 0u) ? 1 : 0;
  if (loc) atomicOr(&any, 1);
  __syncthreads();
  if (threadIdx.x == 0) g_mode = any ? 1 : 0;
}

// K1: Wh = h @ W (fp64 accumulate -> fp32), s1 = Wh@a1, s2 = Wh@a2 (fp32-
// rounded Wh feeding fp64 dot, stored fp32 to mirror the reference's fp32
// quantization for ranking). 4 rows/block, W staged in LDS (64 KB exactly).
template<bool BF16>
__global__ __launch_bounds__(256) void k_wh(
    const void* __restrict__ h, const void* __restrict__ W, const void* __restrict__ a)
{
  if (g_mode != (BF16 ? 1 : 0)) return;
  __shared__ float Ws[F_INN * F_OUTT];   // 64 KB
  const int tid = threadIdx.x;
  for (int idx = tid; idx < F_INN * F_OUTT; idx += 256) Ws[idx] = ldf<BF16>(W, idx);
  __syncthreads();
  const int wave = tid >> 6, lane = tid & 63;
  const int row = blockIdx.x * 4 + wave;
  double acc = 0.0;
  #pragma unroll 8
  for (int k = 0; k < F_INN; k++)
    acc += (double)ldf<BF16>(h, row * F_INN + k) * (double)Ws[k * F_OUTT + lane];
  const float whv = (float)acc;
  g_Wh[row * F_OUTT + lane] = whv;
  double t1 = (double)whv * (double)ldf<BF16>(a, lane);
  double t2 = (double)whv * (double)ldf<BF16>(a, F_OUTT + lane);
  #pragma unroll
  for (int off = 32; off > 0; off >>= 1) {
    t1 += __shfl_down(t1, off);
    t2 += __shfl_down(t2, off);
  }
  if (lane == 0) { g_s1[row] = (float)t1; g_s2[row] = (float)t2; }
}

// K2: per-row attention. Neighbor collect, fp32 scores (mirrors reference
// quantization), fp64 softmax, rank by (att desc, index asc) == stable
// argsort(-att), Wh2 = att @ Wh (fp64 acc), reversed order list (all 64
// slots written so K4 can never read poison).
template<bool BF16>
__global__ __launch_bounds__(256) void k_att(const void* __restrict__ adj)
{
  if (g_mode != (BF16 ? 1 : 0)) return;
  const int i = blockIdx.x, tid = threadIdx.x;
  __shared__ int   nbr[MAXDEG];
  __shared__ float att_s[MAXDEG];
  __shared__ int   sorted_j[MAXDEG];
  __shared__ int   cnt;
  if (tid == 0) cnt = 0;
  __syncthreads();
  if (BF16) {
    const unsigned short* ar = (const unsigned short*)adj + (size_t)i * N_NODES;
    for (int c = tid; c < N_NODES; c += 256)
      if (ar[c] != 0) { int p = atomicAdd(&cnt, 1); if (p < MAXDEG) nbr[p] = c; }
  } else {
    const float* ar = (const float*)adj + (size_t)i * N_NODES;
    for (int c = tid; c < N_NODES; c += 256)
      if (ar[c] != 0.0f) { int p = atomicAdd(&cnt, 1); if (p < MAXDEG) nbr[p] = c; }
  }
  __syncthreads();
  const int L = min(cnt, MAXDEG);   // == seq_length[i]
  float ef = -3.0e38f; int jn = 0x7fffffff;
  if (tid < L) {
    jn = nbr[tid];
    float s = g_s1[i] + g_s2[jn];              // fp32 add, like reference
    ef = (s > 0.0f) ? s : 0.2f * s;            // leaky_relu fp32
  }
  float af = 0.0f;
  if (tid < 64) {  // wave 0 holds all neighbor slots (L <= 64)
    float m = ef;
    #pragma unroll
    for (int off = 32; off > 0; off >>= 1) m = fmaxf(m, __shfl_down(m, off));
    m = __shfl(m, 0);
    double p = (tid < L) ? exp((double)(ef - m)) : 0.0;
    double ssum = p;
    #pragma unroll
    for (int off = 32; off > 0; off >>= 1) ssum += __shfl_down(ssum, off);
    ssum = __shfl(ssum, 0);
    af = (float)(p / ssum);
    att_s[tid] = af;
  }
  __syncthreads();
  if (tid < L) {
    int rank = 0;
    for (int q = 0; q < L; q++) {
      float aq = att_s[q]; int jq = nbr[q];
      if (aq > af || (aq == af && jq < jn)) rank++;
    }
    sorted_j[rank] = jn;
  }
  __syncthreads();
  if (tid < MAXDEG)
    g_rev[i * MAXDEG + tid] = (tid < L) ? sorted_j[L - 1 - tid] : 0;
  if (tid < 64) {
    double acc = 0.0;
    for (int q = 0; q < L; q++)
      acc += (double)att_s[q] * (double)g_Wh[(size_t)nbr[q] * F_OUTT + tid];
    g_Wh2[i * F_OUTT + tid] = (float)acc;
  }
}

// K3: counting sort by seq_length descending (scheduling only).
__global__ __launch_bounds__(256) void k_perm(const int* __restrict__ seq)
{
  __shared__ int hist[MAXDEG + 1];
  __shared__ int offs[MAXDEG + 1];
  const int tid = threadIdx.x;
  if (tid <= MAXDEG) hist[tid] = 0;
  __syncthreads();
  for (int i = tid; i < N_NODES; i += 256)
    atomicAdd(&hist[min(max(seq[i], 0), MAXDEG)], 1);
  __syncthreads();
  if (tid == 0) {
    int run = 0;
    for (int L = MAXDEG; L >= 0; L--) { offs[L] = run; run += hist[L]; }
  }
  __syncthreads();
  for (int i = tid; i < N_NODES; i += 256) {
    int p = atomicAdd(&offs[min(max(seq[i], 0), MAXDEG)], 1);
    g_perm[p] = i;
  }
}

// K3b: GX[n] = Wh2[n] @ w_ih^T, stored as per-unit quads {i,f,g,o}. Hoists
// the input-side matmul out of the sequential LSTM (identical math).
template<bool BF16>
__global__ __launch_bounds__(256) void k_gx(const void* __restrict__ w_ih)
{
  if (g_mode != (BF16 ? 1 : 0)) return;
  __shared__ float xr[F_OUTT];
  const int n = blockIdx.x, t = threadIdx.x;
  if (t < F_OUTT) xr[t] = g_Wh2[n * F_OUTT + t];
  __syncthreads();
  double acc = 0.0;
  #pragma unroll 8
  for (int j = 0; j < F_OUTT; j++)
    acc += (double)ldf<BF16>(w_ih, t * F_OUTT + j) * (double)xr[j];
  ((float*)g_GX)[(n * F_OUTT + (t & 63)) * 4 + (t >> 6)] = (float)acc;
}

// K4: masked LSTM over reversed top-attention sequences. One wave = 4 rows.
// w_hh in LDS as float quads (64 KB exactly); per-step inputs are the
// precomputed GX quads; h broadcast via v_readlane.
template<bool BF16>
__global__ __launch_bounds__(256) void k_lstm(
    const void* __restrict__ w_hh, const void* __restrict__ b_ih,
    const void* __restrict__ b_hh, const int* __restrict__ seq,
    void* __restrict__ out)
{
  if (g_mode != (BF16 ? 1 : 0)) return;
  __shared__ float4 whq[64 * 64];   // 64 KB: whq[j*64+d] = {w_hh[g*64+d][j]}g
  const int tid = threadIdx.x;
  {
    float* ph = (float*)whq;
    for (int idx = tid; idx < 256 * 64; idx += 256) {
      int row = idx >> 6, j = idx & 63;      // row = g*64+d
      int g = row >> 6, d = row & 63;
      ph[(j * 64 + d) * 4 + g] = ldf<BF16>(w_hh, idx);
    }
  }
  __syncthreads();
  const int wave = tid >> 6, lane = tid & 63;
  const int base = (blockIdx.x * 4 + wave) * 4;
  int rows[4], Ls[4];
  #pragma unroll
  for (int r = 0; r < 4; r++) {
    rows[r] = g_perm[base + r] & (N_NODES - 1);
    Ls[r]   = min(max(seq[rows[r]], 0), MAXDEG);
  }
  const int Lmax = max(max(Ls[0], Ls[1]), max(Ls[2], Ls[3]));
  float bsum[4];
  #pragma unroll
  for (int g = 0; g < 4; g++)
    bsum[g] = ldf<BF16>(b_ih, g * 64 + lane) + ldf<BF16>(b_hh, g * 64 + lane);

  float hcur[4] = {0.f,0.f,0.f,0.f}, ccur[4] = {0.f,0.f,0.f,0.f};
  float4 gx[4];
  #pragma unroll
  for (int r = 0; r < 4; r++) gx[r] = make_float4(0.f,0.f,0.f,0.f);

  for (int t = 0; t < Lmax; t++) {
    #pragma unroll
    for (int r = 0; r < 4; r++) {
      if (t < Ls[r]) {
        int src = g_rev[rows[r] * MAXDEG + t] & (N_NODES - 1);
        gx[r] = g_GX[src * F_OUTT + lane];
      }
    }
    float acc[4][4];
    #pragma unroll
    for (int r = 0; r < 4; r++) {
      acc[r][0] = bsum[0] + gx[r].x; acc[r][1] = bsum[1] + gx[r].y;
      acc[r][2] = bsum[2] + gx[r].z; acc[r][3] = bsum[3] + gx[r].w;
    }
    #pragma unroll 8
    for (int j = 0; j < 64; j++) {
      float4 wv = whq[j * 64 + lane];
      #pragma unroll
      for (int r = 0; r < 4; r++) {
        float hv = bcastf(hcur[r], j);
        acc[r][0] = fmaf(wv.x, hv, acc[r][0]);
        acc[r][1] = fmaf(wv.y, hv, acc[r][1]);
        acc[r][2] = fmaf(wv.z, hv, acc[r][2]);
        acc[r][3] = fmaf(wv.w, hv, acc[r][3]);
      }
    }
    #pragma unroll
    for (int r = 0; r < 4; r++) {
      float ig = sigm(acc[r][0]);
      float fg = sigm(acc[r][1]);
      float gg = tanh_fast(acc[r][2]);
      float og = sigm(acc[r][3]);
      float cn = fg * ccur[r] + ig * gg;
      float hn = og * tanh_fast(cn);
      if (t < Ls[r]) { ccur[r] = cn; hcur[r] = hn; }
    }
  }
  #pragma unroll
  for (int r = 0; r < 4; r++) {
    if (BF16) ((__hip_bfloat16*)out)[rows[r] * HID + lane] = __float2bfloat16(hcur[r]);
    else      ((float*)out)[rows[r] * HID + lane] = hcur[r];
  }
}

extern "C" void kernel_launch(void* const* d_in, const int* in_sizes, int n_in,
                              void* d_out, int out_size, void* d_ws, size_t ws_size,
                              hipStream_t stream) {
  (void)in_sizes; (void)n_in; (void)out_size; (void)d_ws; (void)ws_size;
  const void* h    = d_in[0];
  const void* adj  = d_in[1];
  const int*  seq  = (const int*)d_in[2];
  const void* W    = d_in[3];
  const void* a    = d_in[4];
  const void* w_ih = d_in[5];
  const void* w_hh = d_in[6];
  const void* b_ih = d_in[7];
  const void* b_hh = d_in[8];

  k_detect<<<1, 256, 0, stream>>>((const unsigned int*)adj);
  k_wh<false><<<N_NODES / 4, 256, 0, stream>>>(h, W, a);
  k_wh<true> <<<N_NODES / 4, 256, 0, stream>>>(h, W, a);
  k_perm     <<<1,           256, 0, stream>>>(seq);
  k_att<false><<<N_NODES,    256, 0, stream>>>(adj);
  k_att<true> <<<N_NODES,    256, 0, stream>>>(adj);
  k_gx<false> <<<N_NODES,    256, 0, stream>>>(w_ih);
  k_gx<true>  <<<N_NODES,    256, 0, stream>>>(w_ih);
  k_lstm<false><<<N_NODES / 16, 256, 0, stream>>>(w_hh, b_ih, b_hh, seq, d_out);
  k_lstm<true> <<<N_NODES / 16, 256, 0, stream>>>(w_hh, b_ih, b_hh, seq, d_out);
}

// Round 4
// 428.962 us; speedup vs baseline: 1.1858x; 1.1858x over previous
//
#include <hip/hip_runtime.h>
#include <hip/hip_bf16.h>
#include <math.h>

#define N_NODES 4096
#define F_INN   256
#define F_OUTT  64
#define HID     64
#define MAXDEG  64

// Scratch in device globals (no ws_size dependence). Fully rewritten each call.
__device__ int    g_mode;                    // 0 = fp32 inputs, 1 = bf16 inputs
__device__ float  g_Wh [N_NODES * F_OUTT];
__device__ float  g_s1 [N_NODES];
__device__ float  g_s2 [N_NODES];
__device__ int    g_rev[N_NODES * MAXDEG];
__device__ int    g_perm[N_NODES];
__device__ float4 g_GX [N_NODES * F_OUTT];   // per (node, unit): quad {i,f,g,o}

__device__ __forceinline__ float bf2f(unsigned short u) {
  union { unsigned int i; float f; } v; v.i = ((unsigned int)u) << 16; return v.f;
}

template<bool BF16>
__device__ __forceinline__ float ldf(const void* p, int i) {
  if constexpr (BF16) return bf2f(((const unsigned short*)p)[i]);
  else                return ((const float*)p)[i];
}

__device__ __forceinline__ float bcastf(float v, int l) {
#if __has_builtin(__builtin_amdgcn_readlane)
  return __int_as_float(__builtin_amdgcn_readlane(__float_as_int(v), l));
#else
  return __shfl(v, l);
#endif
}

__device__ __forceinline__ float sigm(float x) { return 1.f / (1.f + __expf(-x)); }
__device__ __forceinline__ float tanh_fast(float x) { return 1.f - 2.f / (1.f + __expf(2.f * x)); }

// D0: dtype detector. fp32 adj words are exactly 0x00000000 / 0x3F800000
// (low 16 bits always zero). bf16 adj has ~500 nonzero low-halves in the
// first 65536 words.
__global__ __launch_bounds__(256) void k_detect(const unsigned int* __restrict__ aw) {
  __shared__ int any;
  if (threadIdx.x == 0) any = 0;
  __syncthreads();
  int loc = 0;
  for (int i = threadIdx.x; i < 65536; i += 256)
    loc |= ((aw[i] & 0xFFFFu) != 0u) ? 1 : 0;
  if (loc) atomicOr(&any, 1);
  __syncthreads();
  if (threadIdx.x == 0) g_mode = any ? 1 : 0;
}

// K1: Wh = h @ W (fp64 accumulate -> fp32), s1 = Wh@a1, s2 = Wh@a2.
// Unchanged from round 3 (proven; not a hot spot).
template<bool BF16>
__global__ __launch_bounds__(256) void k_wh(
    const void* __restrict__ h, const void* __restrict__ W, const void* __restrict__ a)
{
  if (g_mode != (BF16 ? 1 : 0)) return;
  __shared__ float Ws[F_INN * F_OUTT];   // 64 KB
  const int tid = threadIdx.x;
  for (int idx = tid; idx < F_INN * F_OUTT; idx += 256) Ws[idx] = ldf<BF16>(W, idx);
  __syncthreads();
  const int wave = tid >> 6, lane = tid & 63;
  const int row = blockIdx.x * 4 + wave;
  double acc = 0.0;
  #pragma unroll 8
  for (int k = 0; k < F_INN; k++)
    acc += (double)ldf<BF16>(h, row * F_INN + k) * (double)Ws[k * F_OUTT + lane];
  const float whv = (float)acc;
  g_Wh[row * F_OUTT + lane] = whv;
  double t1 = (double)whv * (double)ldf<BF16>(a, lane);
  double t2 = (double)whv * (double)ldf<BF16>(a, F_OUTT + lane);
  #pragma unroll
  for (int off = 32; off > 0; off >>= 1) {
    t1 += __shfl_down(t1, off);
    t2 += __shfl_down(t2, off);
  }
  if (lane == 0) { g_s1[row] = (float)t1; g_s2[row] = (float)t2; }
}

// K2: per-row attention + fused GX. Neighbor collect (float4 scan), fp32
// scores, fp64 softmax, stable rank (att desc, index asc), Wh2 = att @ Wh
// (4-wave parallel gather, fp64, deterministic reduce), then
// GX = Wh2 @ w_ih^T fused here (kills the separate k_gx pass).
template<bool BF16>
__global__ __launch_bounds__(256) void k_att(
    const void* __restrict__ adj, const void* __restrict__ w_ih)
{
  if (g_mode != (BF16 ? 1 : 0)) return;
  const int i = blockIdx.x, tid = threadIdx.x;
  __shared__ int    nbr[MAXDEG];
  __shared__ float  att_s[MAXDEG];
  __shared__ int    sorted_j[MAXDEG];
  __shared__ double part[4][F_OUTT];
  __shared__ float  wh2row[F_OUTT];
  __shared__ int    cnt;
  if (tid == 0) cnt = 0;
  __syncthreads();
  if (BF16) {
    const uint4* ar = (const uint4*)((const unsigned short*)adj + (size_t)i * N_NODES);
    for (int c = tid; c < N_NODES / 8; c += 256) {   // 8 bf16 per uint4
      uint4 v = ar[c];
      unsigned int w[4] = {v.x, v.y, v.z, v.w};
      #pragma unroll
      for (int k = 0; k < 4; k++) {
        if (w[k] & 0x0000FFFFu) { int p = atomicAdd(&cnt, 1); if (p < MAXDEG) nbr[p] = c*8 + k*2; }
        if (w[k] & 0xFFFF0000u) { int p = atomicAdd(&cnt, 1); if (p < MAXDEG) nbr[p] = c*8 + k*2 + 1; }
      }
    }
  } else {
    const float4* ar = (const float4*)((const float*)adj + (size_t)i * N_NODES);
    for (int c = tid; c < N_NODES / 4; c += 256) {
      float4 v = ar[c];
      if (v.x != 0.0f) { int p = atomicAdd(&cnt, 1); if (p < MAXDEG) nbr[p] = c*4;     }
      if (v.y != 0.0f) { int p = atomicAdd(&cnt, 1); if (p < MAXDEG) nbr[p] = c*4 + 1; }
      if (v.z != 0.0f) { int p = atomicAdd(&cnt, 1); if (p < MAXDEG) nbr[p] = c*4 + 2; }
      if (v.w != 0.0f) { int p = atomicAdd(&cnt, 1); if (p < MAXDEG) nbr[p] = c*4 + 3; }
    }
  }
  __syncthreads();
  const int L = min(cnt, MAXDEG);   // == seq_length[i]
  float ef = -3.0e38f; int jn = 0x7fffffff;
  if (tid < L) {
    jn = nbr[tid];
    float s = g_s1[i] + g_s2[jn];              // fp32 add, like reference
    ef = (s > 0.0f) ? s : 0.2f * s;            // leaky_relu fp32
  }
  float af = 0.0f;
  if (tid < 64) {  // wave 0 holds all neighbor slots (L <= 64)
    float m = ef;
    #pragma unroll
    for (int off = 32; off > 0; off >>= 1) m = fmaxf(m, __shfl_down(m, off));
    m = __shfl(m, 0);
    double p = (tid < L) ? exp((double)(ef - m)) : 0.0;
    double ssum = p;
    #pragma unroll
    for (int off = 32; off > 0; off >>= 1) ssum += __shfl_down(ssum, off);
    ssum = __shfl(ssum, 0);
    af = (float)(p / ssum);
    att_s[tid] = af;
  }
  __syncthreads();
  if (tid < L) {
    int rank = 0;
    for (int q = 0; q < L; q++) {
      float aq = att_s[q]; int jq = nbr[q];
      if (aq > af || (aq == af && jq < jn)) rank++;
    }
    sorted_j[rank] = jn;
  }
  // Wh2 gather split across all 4 waves (was wave-0-only).
  {
    const int wave = tid >> 6, lane = tid & 63;
    double acc = 0.0;
    for (int q = wave; q < L; q += 4)
      acc += (double)att_s[q] * (double)g_Wh[(size_t)nbr[q] * F_OUTT + lane];
    part[wave][lane] = acc;
  }
  __syncthreads();
  if (tid < MAXDEG)
    g_rev[i * MAXDEG + tid] = (tid < L) ? sorted_j[L - 1 - tid] : 0;
  if (tid < 64)
    wh2row[tid] = (float)(part[0][tid] + part[1][tid] + part[2][tid] + part[3][tid]);
  __syncthreads();
  // Fused GX: gate-row tid (g = tid>>6, d = tid&63): dot(w_ih[tid,:], wh2row)
  {
    double acc = 0.0;
    #pragma unroll 8
    for (int j = 0; j < F_OUTT; j++)
      acc += (double)ldf<BF16>(w_ih, tid * F_OUTT + j) * (double)wh2row[j];
    ((float*)g_GX)[(i * F_OUTT + (tid & 63)) * 4 + (tid >> 6)] = (float)acc;
  }
}

// K3: counting sort by seq_length descending (scheduling only).
__global__ __launch_bounds__(256) void k_perm(const int* __restrict__ seq)
{
  __shared__ int hist[MAXDEG + 1];
  __shared__ int offs[MAXDEG + 1];
  const int tid = threadIdx.x;
  if (tid <= MAXDEG) hist[tid] = 0;
  __syncthreads();
  for (int i = tid; i < N_NODES; i += 256)
    atomicAdd(&hist[min(max(seq[i], 0), MAXDEG)], 1);
  __syncthreads();
  if (tid == 0) {
    int run = 0;
    for (int L = MAXDEG; L >= 0; L--) { offs[L] = run; run += hist[L]; }
  }
  __syncthreads();
  for (int i = tid; i < N_NODES; i += 256) {
    int p = atomicAdd(&offs[min(max(seq[i], 0), MAXDEG)], 1);
    g_perm[p] = i;
  }
}

// K4 v2: masked LSTM. One wave = 4 rows (sorted quads -> uniform intra-wave L).
// Changes vs round 3: (a) gx software-pipelined one step ahead with
// UNCONDITIONAL loads (masked steps discard via cndmask -> no exec-mask
// branches, L2 latency hidden behind the j-loop); (b) weight quads for
// j=0..31 held in 128 VGPRs (halves per-step LDS reads + waits).
template<bool BF16>
__global__ __launch_bounds__(256) void k_lstm(
    const void* __restrict__ w_hh, const void* __restrict__ b_ih,
    const void* __restrict__ b_hh, const int* __restrict__ seq,
    void* __restrict__ out)
{
  if (g_mode != (BF16 ? 1 : 0)) return;
  __shared__ float4 whq[64 * 64];   // 64 KB: whq[j*64+d] = {w_hh[g*64+d][j]}g
  const int tid = threadIdx.x;
  {
    float* ph = (float*)whq;
    for (int idx = tid; idx < 256 * 64; idx += 256) {
      int row = idx >> 6, j = idx & 63;      // row = g*64+d
      int g = row >> 6, d = row & 63;
      ph[(j * 64 + d) * 4 + g] = ldf<BF16>(w_hh, idx);
    }
  }
  __syncthreads();
  const int wave = tid >> 6, lane = tid & 63;

  // j=0..31 weight quads -> registers (128 VGPRs)
  float4 wr[32];
  #pragma unroll
  for (int j = 0; j < 32; j++) wr[j] = whq[j * 64 + lane];

  const int base = (blockIdx.x * 4 + wave) * 4;
  int rows[4], Ls[4];
  #pragma unroll
  for (int r = 0; r < 4; r++) {
    rows[r] = g_perm[base + r] & (N_NODES - 1);
    Ls[r]   = min(max(seq[rows[r]], 0), MAXDEG);
  }
  const int Lmax = max(max(Ls[0], Ls[1]), max(Ls[2], Ls[3]));
  float bsum[4];
  #pragma unroll
  for (int g = 0; g < 4; g++)
    bsum[g] = ldf<BF16>(b_ih, g * 64 + lane) + ldf<BF16>(b_hh, g * 64 + lane);

  float hcur[4] = {0.f,0.f,0.f,0.f}, ccur[4] = {0.f,0.f,0.f,0.f};
  float4 gx[4];
  #pragma unroll
  for (int r = 0; r < 4; r++) {
    int src0 = g_rev[rows[r] * MAXDEG] & (N_NODES - 1);
    gx[r] = g_GX[src0 * F_OUTT + lane];
  }

  for (int t = 0; t < Lmax; t++) {
    // prefetch next step's gx (unconditional; masked steps ignore it)
    float4 gxn[4];
    #pragma unroll
    for (int r = 0; r < 4; r++) {
      int idxn = rows[r] * MAXDEG + ((t + 1) & (MAXDEG - 1));
      int srcn = g_rev[idxn] & (N_NODES - 1);
      gxn[r] = g_GX[srcn * F_OUTT + lane];
    }
    float acc[4][4];
    #pragma unroll
    for (int r = 0; r < 4; r++) {
      acc[r][0] = bsum[0] + gx[r].x; acc[r][1] = bsum[1] + gx[r].y;
      acc[r][2] = bsum[2] + gx[r].z; acc[r][3] = bsum[3] + gx[r].w;
    }
    // j = 0..31 from registers
    #pragma unroll
    for (int j = 0; j < 32; j++) {
      float4 wv = wr[j];
      #pragma unroll
      for (int r = 0; r < 4; r++) {
        float hv = bcastf(hcur[r], j);
        acc[r][0] = fmaf(wv.x, hv, acc[r][0]);
        acc[r][1] = fmaf(wv.y, hv, acc[r][1]);
        acc[r][2] = fmaf(wv.z, hv, acc[r][2]);
        acc[r][3] = fmaf(wv.w, hv, acc[r][3]);
      }
    }
    // j = 32..63 from LDS
    #pragma unroll 8
    for (int j = 32; j < 64; j++) {
      float4 wv = whq[j * 64 + lane];
      #pragma unroll
      for (int r = 0; r < 4; r++) {
        float hv = bcastf(hcur[r], j);
        acc[r][0] = fmaf(wv.x, hv, acc[r][0]);
        acc[r][1] = fmaf(wv.y, hv, acc[r][1]);
        acc[r][2] = fmaf(wv.z, hv, acc[r][2]);
        acc[r][3] = fmaf(wv.w, hv, acc[r][3]);
      }
    }
    #pragma unroll
    for (int r = 0; r < 4; r++) {
      float ig = sigm(acc[r][0]);
      float fg = sigm(acc[r][1]);
      float gg = tanh_fast(acc[r][2]);
      float og = sigm(acc[r][3]);
      float cn = fg * ccur[r] + ig * gg;
      float hn = og * tanh_fast(cn);
      bool live = (t < Ls[r]);
      ccur[r] = live ? cn : ccur[r];
      hcur[r] = live ? hn : hcur[r];
      gx[r] = gxn[r];
    }
  }
  #pragma unroll
  for (int r = 0; r < 4; r++) {
    if (BF16) ((__hip_bfloat16*)out)[rows[r] * HID + lane] = __float2bfloat16(hcur[r]);
    else      ((float*)out)[rows[r] * HID + lane] = hcur[r];
  }
}

extern "C" void kernel_launch(void* const* d_in, const int* in_sizes, int n_in,
                              void* d_out, int out_size, void* d_ws, size_t ws_size,
                              hipStream_t stream) {
  (void)in_sizes; (void)n_in; (void)out_size; (void)d_ws; (void)ws_size;
  const void* h    = d_in[0];
  const void* adj  = d_in[1];
  const int*  seq  = (const int*)d_in[2];
  const void* W    = d_in[3];
  const void* a    = d_in[4];
  const void* w_ih = d_in[5];
  const void* w_hh = d_in[6];
  const void* b_ih = d_in[7];
  const void* b_hh = d_in[8];

  k_detect<<<1, 256, 0, stream>>>((const unsigned int*)adj);
  k_wh<false><<<N_NODES / 4, 256, 0, stream>>>(h, W, a);
  k_wh<true> <<<N_NODES / 4, 256, 0, stream>>>(h, W, a);
  k_perm     <<<1,           256, 0, stream>>>(seq);
  k_att<false><<<N_NODES,    256, 0, stream>>>(adj, w_ih);
  k_att<true> <<<N_NODES,    256, 0, stream>>>(adj, w_ih);
  k_lstm<false><<<N_NODES / 16, 256, 0, stream>>>(w_hh, b_ih, b_hh, seq, d_out);
  k_lstm<true> <<<N_NODES / 16, 256, 0, stream>>>(w_hh, b_ih, b_hh, seq, d_out);
}